// Round 1
// baseline (307.725 us; speedup 1.0000x reference)
//
#include <hip/hip_runtime.h>
#include <hip/hip_bf16.h>

// Problem: B=2, S=2048, DIM=1536, H=12, HD=128
//   q = rope(rms(x@wq.T + bq, gq)); k likewise; v = x@wv.T + bv
//   attn per head, out = attn_out @ wo.T + bo   (all fp32 reference)
// Strategy: bf16 MFMA pipeline (threshold = 2% of ref max, plenty of headroom).

#define BQ  2
#define SQ  2048
#define DIMQ 1536
#define HQ  12
#define HDQ 128
#define MTOK 4096          // B*S
#define KDIM 1536

typedef __attribute__((ext_vector_type(8))) short short8;   // 8 x bf16 (4 VGPR)
typedef __attribute__((ext_vector_type(4))) float f32x4;
typedef __attribute__((ext_vector_type(8))) unsigned short u16x8;

typedef __attribute__((address_space(1))) const void global_cvoid;
typedef __attribute__((address_space(3))) void lds_void;

__device__ __forceinline__ float bf2f(unsigned int u) {
    return __uint_as_float(u << 16);
}
__device__ __forceinline__ unsigned short f2bf(float f) {
    unsigned int u = __float_as_uint(f);
    u += 0x7fffu + ((u >> 16) & 1u);   // round-to-nearest-even
    return (unsigned short)(u >> 16);
}
__device__ __forceinline__ void gload_lds16(const void* g, void* l) {
    __builtin_amdgcn_global_load_lds((global_cvoid*)g, (lds_void*)l, 16, 0, 0);
}

// ---------------------------------------------------------------- cast f32->bf16
__global__ __launch_bounds__(256)
void cast_f32_bf16(const float* __restrict__ src, unsigned short* __restrict__ dst, int n4) {
    int i = blockIdx.x * blockDim.x + threadIdx.x;
    int stride = gridDim.x * blockDim.x;
    for (; i < n4; i += stride) {
        float4 v = ((const float4*)src)[i];
        unsigned short a = f2bf(v.x), b = f2bf(v.y), c = f2bf(v.z), d = f2bf(v.w);
        unsigned int lo = (unsigned int)a | ((unsigned int)b << 16);
        unsigned int hi = (unsigned int)c | ((unsigned int)d << 16);
        ((uint2*)dst)[i] = make_uint2(lo, hi);
    }
}

// ---------------------------------------------------------------- GEMM C = A * B^T  (+bias)
// A: [M x 1536] bf16 row-major, Bm: [N x 1536] bf16 row-major (weight rows).
// MODE 0: N=4608 (q|k|v concat) -> bf16 out into oQ/oK/oV with per-segment bias.
// MODE 1: N=1536 -> fp32 out (d_out) + bias.
// 128x128 tile, BK=64, 4 waves (2x2 of 64x64), single-buffer LDS w/ XOR swizzle.
template<int MODE>
__global__ __launch_bounds__(256)
void gemm_bt(const unsigned short* __restrict__ A,
             const unsigned short* __restrict__ Bm,
             unsigned short* __restrict__ oQ,
             unsigned short* __restrict__ oK,
             unsigned short* __restrict__ oV,
             const float* __restrict__ biasq,
             const float* __restrict__ biask,
             const float* __restrict__ biasv,
             float* __restrict__ oF,
             const float* __restrict__ biaso)
{
    __shared__ unsigned short ldsA[128 * 64];   // 16 KB
    __shared__ unsigned short ldsB[128 * 64];   // 16 KB
    const int m0 = blockIdx.x * 128;
    const int n0 = blockIdx.y * 128;
    const int t = threadIdx.x;
    const int lane = t & 63;
    const int wid = t >> 6;
    const int wr = (wid >> 1) * 64;
    const int wc = (wid & 1) * 64;
    const int lr = lane & 15;
    const int lk = lane >> 4;

    f32x4 acc[4][4] = {};

    #pragma unroll 1
    for (int kt = 0; kt < KDIM; kt += 64) {
        // stage A-tile [128][64] and B-tile [128][64]; rows are 128B = 8 chunks of 16B.
        // LDS stays linear; the XOR swizzle (chunk ^ (row&7)) is applied on the
        // per-lane GLOBAL source so reads below use the same involution.
        #pragma unroll
        for (int i = 0; i < 4; ++i) {
            const int off = i * 4096 + wid * 1024 + lane * 16;  // byte offset in tile
            const int r = off >> 7;
            const int c = (off >> 4) & 7;
            const int csw = (c ^ (r & 7)) << 3;                 // element offset in row
            gload_lds16(A + (size_t)(m0 + r) * KDIM + kt + csw,
                        (char*)ldsA + i * 4096 + wid * 1024);
            gload_lds16(Bm + (size_t)(n0 + r) * KDIM + kt + csw,
                        (char*)ldsB + i * 4096 + wid * 1024);
        }
        __syncthreads();   // drains vmcnt before barrier (compiler-inserted)

        #pragma unroll
        for (int kk = 0; kk < 2; ++kk) {
            short8 af[4], bf[4];
            #pragma unroll
            for (int mi = 0; mi < 4; ++mi) {
                int row = wr + mi * 16 + lr;
                int ch = (kk * 4 + lk) ^ (row & 7);
                af[mi] = *(const short8*)((const char*)ldsA + row * 128 + ch * 16);
            }
            #pragma unroll
            for (int ni = 0; ni < 4; ++ni) {
                int row = wc + ni * 16 + lr;
                int ch = (kk * 4 + lk) ^ (row & 7);
                bf[ni] = *(const short8*)((const char*)ldsB + row * 128 + ch * 16);
            }
            #pragma unroll
            for (int mi = 0; mi < 4; ++mi)
                #pragma unroll
                for (int ni = 0; ni < 4; ++ni)
                    acc[mi][ni] = __builtin_amdgcn_mfma_f32_16x16x32_bf16(
                        af[mi], bf[ni], acc[mi][ni], 0, 0, 0);
        }
        __syncthreads();
    }

    // epilogue: D layout col=lane&15, row=(lane>>4)*4+j  [m89-verified]
    if (MODE == 0) {
        const int seg = n0 / 1536;
        unsigned short* op = (seg == 0) ? oQ : (seg == 1 ? oK : oV);
        const float* bp = (seg == 0) ? biasq : (seg == 1 ? biask : biasv);
        const int nl0 = n0 - seg * 1536;
        #pragma unroll
        for (int mi = 0; mi < 4; ++mi)
            #pragma unroll
            for (int ni = 0; ni < 4; ++ni)
                #pragma unroll
                for (int j = 0; j < 4; ++j) {
                    int row = m0 + wr + mi * 16 + lk * 4 + j;
                    int col = nl0 + wc + ni * 16 + lr;
                    op[(size_t)row * 1536 + col] = f2bf(acc[mi][ni][j] + bp[col]);
                }
    } else {
        #pragma unroll
        for (int mi = 0; mi < 4; ++mi)
            #pragma unroll
            for (int ni = 0; ni < 4; ++ni)
                #pragma unroll
                for (int j = 0; j < 4; ++j) {
                    int row = m0 + wr + mi * 16 + lk * 4 + j;
                    int col = n0 + wc + ni * 16 + lr;
                    oF[(size_t)row * 1536 + col] = acc[mi][ni][j] + biaso[col];
                }
    }
}

// ---------------------------------------------------------------- RMSNorm (full row) + RoPE, in place
// One block per token row of 1536 bf16. Each thread owns 3 pairs.
__global__ __launch_bounds__(256)
void rmsnorm_rope(unsigned short* __restrict__ T,
                  const float* __restrict__ g,
                  const float* __restrict__ freqs)
{
    const int token = blockIdx.x;          // 0..4095
    const int s = token & (SQ - 1);
    unsigned int* row = (unsigned int*)(T + (size_t)token * DIMQ);
    const int t = threadIdx.x;
    const int lane = t & 63, wid = t >> 6;

    float pr[3], pi[3];
    float ss = 0.f;
    #pragma unroll
    for (int q = 0; q < 3; ++q) {
        unsigned int v = row[t + q * 256];
        float a = bf2f(v & 0xffffu);
        float b = bf2f(v >> 16);
        pr[q] = a; pi[q] = b;
        ss += a * a + b * b;
    }
    ss += __shfl_xor(ss, 32); ss += __shfl_xor(ss, 16); ss += __shfl_xor(ss, 8);
    ss += __shfl_xor(ss, 4);  ss += __shfl_xor(ss, 2);  ss += __shfl_xor(ss, 1);
    __shared__ float red[4];
    if (lane == 0) red[wid] = ss;
    __syncthreads();
    float tot = red[0] + red[1] + red[2] + red[3];
    float sc = rsqrtf(tot * (1.0f / 1536.0f) + 1e-6f);

    #pragma unroll
    for (int q = 0; q < 3; ++q) {
        int p = t + q * 256;               // global pair index 0..767
        int ph = p & 63;                   // pair-in-head
        float fr = freqs[s * 128 + ph * 2];
        float fi = freqs[s * 128 + ph * 2 + 1];
        float nr = pr[q] * sc * g[2 * p];
        float ni = pi[q] * sc * g[2 * p + 1];
        float outr = nr * fr - ni * fi;
        float outi = nr * fi + ni * fr;
        row[p] = (unsigned int)f2bf(outr) | ((unsigned int)f2bf(outi) << 16);
    }
}

// ---------------------------------------------------------------- V transpose: [B,S,H,HD] -> [B*H, HD, S]
__global__ __launch_bounds__(256)
void vtrans(const unsigned short* __restrict__ V, unsigned short* __restrict__ Vt)
{
    __shared__ unsigned short tile[64][72];   // +8 pad
    const int s0 = blockIdx.x * 64;
    const int d0 = blockIdx.y * 64;
    const int bh = blockIdx.z;
    const int b = bh / HQ, h = bh % HQ;
    const int t = threadIdx.x;

    #pragma unroll
    for (int i = 0; i < 2; ++i) {
        int cid = i * 256 + t;
        int r = cid >> 3, c = cid & 7;
        u16x8 v = *(const u16x8*)(V + (size_t)(b * SQ + s0 + r) * DIMQ + h * HDQ + d0 + c * 8);
        #pragma unroll
        for (int e = 0; e < 8; ++e) tile[r][c * 8 + e] = v[e];
    }
    __syncthreads();
    #pragma unroll
    for (int i = 0; i < 2; ++i) {
        int cid = i * 256 + t;
        int rd = cid >> 3, c = cid & 7;
        u16x8 w;
        #pragma unroll
        for (int e = 0; e < 8; ++e) w[e] = tile[c * 8 + e][rd];
        *(u16x8*)(Vt + (size_t)(bh * HDQ + d0 + rd) * SQ + s0 + c * 8) = w;
    }
}

// ---------------------------------------------------------------- flash attention
// Block = 4 waves = 64 Q-rows; wave owns 16 rows. KVBLK=64. Online softmax.
__global__ __launch_bounds__(256)
void attn(const unsigned short* __restrict__ Q,
          const unsigned short* __restrict__ Kb,
          const unsigned short* __restrict__ Vt,
          unsigned short* __restrict__ Ao)
{
    __shared__ char smem[40960];
    char* Kl = smem;            // [64][128] bf16, 256B rows, swizzled chunks
    char* Vl = smem + 16384;    // [128][64] bf16 (d-major), 128B rows, swizzled
    char* Pl = smem + 32768;    // [64][64] bf16, 128B rows, swizzled (wave-private rows)

    const int s0 = blockIdx.x * 64;
    const int bh = blockIdx.y;
    const int b = bh / HQ, h = bh % HQ;
    const int t = threadIdx.x;
    const int lane = t & 63, wid = t >> 6;
    const int lr = lane & 15, lk = lane >> 4;
    const float scale = 0.08838834764831845f;   // 1/sqrt(128)

    // Q fragments stay in registers: A-frag row = lane&15, k = (lane>>4)*8
    short8 qf[4];
    const int qrow = b * SQ + s0 + wid * 16 + lr;
    #pragma unroll
    for (int kk = 0; kk < 4; ++kk)
        qf[kk] = *(const short8*)(Q + (size_t)qrow * DIMQ + h * HDQ + kk * 32 + lk * 8);

    float mrun[4], lsum[4];
    f32x4 oAcc[8] = {};
    #pragma unroll
    for (int j = 0; j < 4; ++j) { mrun[j] = -1e30f; lsum[j] = 0.f; }

    const unsigned short* Kbase = Kb + (size_t)(b * SQ) * DIMQ + h * HDQ;
    const unsigned short* Vbase = Vt + (size_t)(bh * HDQ) * SQ;

    #pragma unroll 1
    for (int kv = 0; kv < SQ; kv += 64) {
        // stage K [64][128] (16KB) and V^T [128][64] (16KB)
        #pragma unroll
        for (int i = 0; i < 4; ++i) {
            const int off = i * 4096 + wid * 1024 + lane * 16;
            {   // K: rows 256B = 16 chunks
                int r = off >> 8;
                int c = (off >> 4) & 15;
                gload_lds16(Kbase + (size_t)(kv + r) * DIMQ + ((c ^ (r & 7)) << 3),
                            Kl + i * 4096 + wid * 1024);
            }
            {   // Vt: rows 128B = 8 chunks
                int r = off >> 7;
                int c = (off >> 4) & 7;
                gload_lds16(Vbase + (size_t)r * SQ + kv + ((c ^ (r & 7)) << 3),
                            Vl + i * 4096 + wid * 1024);
            }
        }
        __syncthreads();

        // S = Q K^T : wave computes rows [wid*16,+16) x cols [0,64)
        f32x4 sacc[4];
        #pragma unroll
        for (int ct = 0; ct < 4; ++ct) {
            f32x4 a = {0.f, 0.f, 0.f, 0.f};
            #pragma unroll
            for (int kk = 0; kk < 4; ++kk) {
                int j = ct * 16 + lr;                       // kv row (B-frag col)
                int ch = (kk * 4 + lk) ^ (j & 7);
                short8 kf = *(const short8*)(Kl + j * 256 + ch * 16);
                a = __builtin_amdgcn_mfma_f32_16x16x32_bf16(qf[kk], kf, a, 0, 0, 0);
            }
            sacc[ct] = a;
        }

        // online softmax: lane holds rows (lk*4+j), col lr (+16*ct)
        unsigned short pvals[4][4];
        #pragma unroll
        for (int j = 0; j < 4; ++j) {
            float mx = fmaxf(fmaxf(sacc[0][j], sacc[1][j]), fmaxf(sacc[2][j], sacc[3][j]));
            mx = fmaxf(mx, __shfl_xor(mx, 1));
            mx = fmaxf(mx, __shfl_xor(mx, 2));
            mx = fmaxf(mx, __shfl_xor(mx, 4));
            mx = fmaxf(mx, __shfl_xor(mx, 8));
            mx *= scale;
            float mn = fmaxf(mrun[j], mx);
            float alpha = __expf(mrun[j] - mn);
            mrun[j] = mn;
            float rs = 0.f;
            #pragma unroll
            for (int ct = 0; ct < 4; ++ct) {
                float p = __expf(sacc[ct][j] * scale - mn);
                rs += p;
                pvals[ct][j] = f2bf(p);
            }
            rs += __shfl_xor(rs, 1); rs += __shfl_xor(rs, 2);
            rs += __shfl_xor(rs, 4); rs += __shfl_xor(rs, 8);
            lsum[j] = lsum[j] * alpha + rs;
            #pragma unroll
            for (int nt = 0; nt < 8; ++nt) oAcc[nt][j] *= alpha;
        }

        // write P (bf16) to wave-private LDS rows, swizzled
        #pragma unroll
        for (int j = 0; j < 4; ++j) {
            int prow = wid * 16 + lk * 4 + j;
            #pragma unroll
            for (int ct = 0; ct < 4; ++ct) {
                int col = ct * 16 + lr;
                int ch = (col >> 3) ^ (prow & 7);
                *(unsigned short*)(Pl + prow * 128 + ch * 16 + (col & 7) * 2) = pvals[ct][j];
            }
        }

        // O += P V  (same-wave LDS write->read; HW/compiler order + lgkmcnt)
        #pragma unroll
        for (int kk = 0; kk < 2; ++kk) {
            int rp = wid * 16 + lr;
            int chp = (kk * 4 + lk) ^ (rp & 7);
            short8 pa = *(const short8*)(Pl + rp * 128 + chp * 16);
            #pragma unroll
            for (int nt = 0; nt < 8; ++nt) {
                int d = nt * 16 + lr;
                int cv = (kk * 4 + lk) ^ (d & 7);
                short8 vb = *(const short8*)(Vl + d * 128 + cv * 16);
                oAcc[nt] = __builtin_amdgcn_mfma_f32_16x16x32_bf16(pa, vb, oAcc[nt], 0, 0, 0);
            }
        }
        __syncthreads();   // protect K/V LDS before next stage
    }

    // epilogue: normalize and write bf16 [B,S,DIM]
    #pragma unroll
    for (int nt = 0; nt < 8; ++nt)
        #pragma unroll
        for (int j = 0; j < 4; ++j) {
            int row = s0 + wid * 16 + lk * 4 + j;
            int col = h * HDQ + nt * 16 + lr;
            float v = oAcc[nt][j] / lsum[j];
            Ao[(size_t)(b * SQ + row) * DIMQ + col] = f2bf(v);
        }
}

// ---------------------------------------------------------------- launch
extern "C" void kernel_launch(void* const* d_in, const int* in_sizes, int n_in,
                              void* d_out, int out_size, void* d_ws, size_t ws_size,
                              hipStream_t stream) {
    (void)in_sizes; (void)n_in; (void)out_size; (void)ws_size;
    const float* x     = (const float*)d_in[0];
    const float* freqs = (const float*)d_in[1];
    const float* wq = (const float*)d_in[2];
    const float* bq = (const float*)d_in[3];
    const float* wk = (const float*)d_in[4];
    const float* bk = (const float*)d_in[5];
    const float* wv = (const float*)d_in[6];
    const float* bv = (const float*)d_in[7];
    const float* wo = (const float*)d_in[8];
    const float* bo = (const float*)d_in[9];
    const float* gq = (const float*)d_in[10];
    const float* gk = (const float*)d_in[11];
    float* out = (float*)d_out;

    char* w = (char*)d_ws;
    unsigned short* Xb   = (unsigned short*)(w);               // 4096x1536 bf16
    unsigned short* Wqkv = (unsigned short*)(w + 12582912);    // 4608x1536 bf16
    unsigned short* Wob  = (unsigned short*)(w + 26738688);    // 1536x1536 bf16
    unsigned short* Qb   = (unsigned short*)(w + 31457280);    // 4096x1536 bf16
    unsigned short* Kbuf = (unsigned short*)(w + 44040192);    // 4096x1536 bf16
    unsigned short* Vb   = (unsigned short*)(w + 56623104);    // 4096x1536 bf16
    unsigned short* Vt   = (unsigned short*)(w + 69206016);    // 24x128x2048 bf16
    unsigned short* Ao   = Xb;   // Xb dead after GEMM1 -> reuse for attention out

    cast_f32_bf16<<<2048, 256, 0, stream>>>(x,  Xb,            6291456 / 4);
    cast_f32_bf16<<<1024, 256, 0, stream>>>(wq, Wqkv,          2359296 / 4);
    cast_f32_bf16<<<1024, 256, 0, stream>>>(wk, Wqkv + 2359296, 2359296 / 4);
    cast_f32_bf16<<<1024, 256, 0, stream>>>(wv, Wqkv + 4718592, 2359296 / 4);
    cast_f32_bf16<<<1024, 256, 0, stream>>>(wo, Wob,           2359296 / 4);

    gemm_bt<0><<<dim3(32, 36), 256, 0, stream>>>(
        Xb, Wqkv, Qb, Kbuf, Vb, bq, bk, bv, nullptr, nullptr);

    rmsnorm_rope<<<4096, 256, 0, stream>>>(Qb,   gq, freqs);
    rmsnorm_rope<<<4096, 256, 0, stream>>>(Kbuf, gk, freqs);
    vtrans<<<dim3(32, 2, 24), 256, 0, stream>>>(Vb, Vt);

    attn<<<dim3(32, 24), 256, 0, stream>>>(Qb, Kbuf, Vt, Ao);

    gemm_bt<1><<<dim3(32, 12), 256, 0, stream>>>(
        Ao, Wob, nullptr, nullptr, nullptr, nullptr, nullptr, nullptr, out, bo);
}

// Round 3
// 283.366 us; speedup vs baseline: 1.0860x; 1.0860x over previous
//
#include <hip/hip_runtime.h>
#include <hip/hip_bf16.h>

// Problem: B=2, S=2048, DIM=1536, H=12, HD=128
//   q = rope(rms(x@wq.T + bq, gq)); k likewise; v = x@wv.T + bv
//   attn per head, out = attn_out @ wo.T + bo   (all fp32 reference)
// Strategy: bf16 MFMA pipeline (threshold = 2% of ref max, plenty of headroom).

#define BQ  2
#define SQ  2048
#define DIMQ 1536
#define HQ  12
#define HDQ 128
#define MTOK 4096          // B*S
#define KDIM 1536

typedef __attribute__((ext_vector_type(8))) short short8;   // 8 x bf16 (4 VGPR)
typedef __attribute__((ext_vector_type(4))) float f32x4;
typedef __attribute__((ext_vector_type(16))) float f32x16;
typedef __attribute__((ext_vector_type(8))) unsigned short u16x8;

typedef __attribute__((address_space(1))) const void global_cvoid;
typedef __attribute__((address_space(3))) void lds_void;

__device__ __forceinline__ float bf2f(unsigned int u) {
    return __uint_as_float(u << 16);
}
__device__ __forceinline__ unsigned short f2bf(float f) {
    unsigned int u = __float_as_uint(f);
    u += 0x7fffu + ((u >> 16) & 1u);   // round-to-nearest-even
    return (unsigned short)(u >> 16);
}
__device__ __forceinline__ void gload_lds16(const void* g, void* l) {
    __builtin_amdgcn_global_load_lds((global_cvoid*)g, (lds_void*)l, 16, 0, 0);
}
__device__ __forceinline__ unsigned int cvtpk_bf16(float lo, float hi) {
    unsigned int r;
    asm("v_cvt_pk_bf16_f32 %0, %1, %2" : "=v"(r) : "v"(lo), "v"(hi));
    return r;
}

// ---------------------------------------------------------------- cast f32->bf16
__global__ __launch_bounds__(256)
void cast_f32_bf16(const float* __restrict__ src, unsigned short* __restrict__ dst, int n4) {
    int i = blockIdx.x * blockDim.x + threadIdx.x;
    int stride = gridDim.x * blockDim.x;
    for (; i < n4; i += stride) {
        float4 v = ((const float4*)src)[i];
        unsigned short a = f2bf(v.x), b = f2bf(v.y), c = f2bf(v.z), d = f2bf(v.w);
        unsigned int lo = (unsigned int)a | ((unsigned int)b << 16);
        unsigned int hi = (unsigned int)c | ((unsigned int)d << 16);
        ((uint2*)dst)[i] = make_uint2(lo, hi);
    }
}

// ---------------------------------------------------------------- GEMM C = A * B^T  (+bias)
// A: [M x 1536] bf16 row-major, Bm: [N x 1536] bf16 row-major (weight rows).
// MODE 0: N=4608 (q|k|v concat) -> bf16 out into oQ/oK/oV with per-segment bias.
// MODE 1: N=1536 -> fp32 out (d_out) + bias.
// 128x128 tile, BK=64, 4 waves (2x2 of 64x64), single-buffer LDS w/ XOR swizzle.
template<int MODE>
__global__ __launch_bounds__(256)
void gemm_bt(const unsigned short* __restrict__ A,
             const unsigned short* __restrict__ Bm,
             unsigned short* __restrict__ oQ,
             unsigned short* __restrict__ oK,
             unsigned short* __restrict__ oV,
             const float* __restrict__ biasq,
             const float* __restrict__ biask,
             const float* __restrict__ biasv,
             float* __restrict__ oF,
             const float* __restrict__ biaso)
{
    __shared__ unsigned short ldsA[128 * 64];   // 16 KB
    __shared__ unsigned short ldsB[128 * 64];   // 16 KB
    const int m0 = blockIdx.x * 128;
    const int n0 = blockIdx.y * 128;
    const int t = threadIdx.x;
    const int lane = t & 63;
    const int wid = t >> 6;
    const int wr = (wid >> 1) * 64;
    const int wc = (wid & 1) * 64;
    const int lr = lane & 15;
    const int lk = lane >> 4;

    f32x4 acc[4][4] = {};

    #pragma unroll 1
    for (int kt = 0; kt < KDIM; kt += 64) {
        #pragma unroll
        for (int i = 0; i < 4; ++i) {
            const int off = i * 4096 + wid * 1024 + lane * 16;  // byte offset in tile
            const int r = off >> 7;
            const int c = (off >> 4) & 7;
            const int csw = (c ^ (r & 7)) << 3;                 // element offset in row
            gload_lds16(A + (size_t)(m0 + r) * KDIM + kt + csw,
                        (char*)ldsA + i * 4096 + wid * 1024);
            gload_lds16(Bm + (size_t)(n0 + r) * KDIM + kt + csw,
                        (char*)ldsB + i * 4096 + wid * 1024);
        }
        __syncthreads();

        #pragma unroll
        for (int kk = 0; kk < 2; ++kk) {
            short8 af[4], bf[4];
            #pragma unroll
            for (int mi = 0; mi < 4; ++mi) {
                int row = wr + mi * 16 + lr;
                int ch = (kk * 4 + lk) ^ (row & 7);
                af[mi] = *(const short8*)((const char*)ldsA + row * 128 + ch * 16);
            }
            #pragma unroll
            for (int ni = 0; ni < 4; ++ni) {
                int row = wc + ni * 16 + lr;
                int ch = (kk * 4 + lk) ^ (row & 7);
                bf[ni] = *(const short8*)((const char*)ldsB + row * 128 + ch * 16);
            }
            #pragma unroll
            for (int mi = 0; mi < 4; ++mi)
                #pragma unroll
                for (int ni = 0; ni < 4; ++ni)
                    acc[mi][ni] = __builtin_amdgcn_mfma_f32_16x16x32_bf16(
                        af[mi], bf[ni], acc[mi][ni], 0, 0, 0);
        }
        __syncthreads();
    }

    // epilogue: D layout col=lane&15, row=(lane>>4)*4+j  [m89-verified]
    if (MODE == 0) {
        const int seg = n0 / 1536;
        unsigned short* op = (seg == 0) ? oQ : (seg == 1 ? oK : oV);
        const float* bp = (seg == 0) ? biasq : (seg == 1 ? biask : biasv);
        const int nl0 = n0 - seg * 1536;
        #pragma unroll
        for (int mi = 0; mi < 4; ++mi)
            #pragma unroll
            for (int ni = 0; ni < 4; ++ni)
                #pragma unroll
                for (int j = 0; j < 4; ++j) {
                    int row = m0 + wr + mi * 16 + lk * 4 + j;
                    int col = nl0 + wc + ni * 16 + lr;
                    op[(size_t)row * 1536 + col] = f2bf(acc[mi][ni][j] + bp[col]);
                }
    } else {
        #pragma unroll
        for (int mi = 0; mi < 4; ++mi)
            #pragma unroll
            for (int ni = 0; ni < 4; ++ni)
                #pragma unroll
                for (int j = 0; j < 4; ++j) {
                    int row = m0 + wr + mi * 16 + lk * 4 + j;
                    int col = n0 + wc + ni * 16 + lr;
                    oF[(size_t)row * 1536 + col] = acc[mi][ni][j] + biaso[col];
                }
    }
}

// ---------------------------------------------------------------- RMSNorm (full row) + RoPE, in place
__global__ __launch_bounds__(256)
void rmsnorm_rope(unsigned short* __restrict__ T,
                  const float* __restrict__ g,
                  const float* __restrict__ freqs)
{
    const int token = blockIdx.x;          // 0..4095
    const int s = token & (SQ - 1);
    unsigned int* row = (unsigned int*)(T + (size_t)token * DIMQ);
    const int t = threadIdx.x;
    const int lane = t & 63, wid = t >> 6;

    float pr[3], pi[3];
    float ss = 0.f;
    #pragma unroll
    for (int q = 0; q < 3; ++q) {
        unsigned int v = row[t + q * 256];
        float a = bf2f(v & 0xffffu);
        float b = bf2f(v >> 16);
        pr[q] = a; pi[q] = b;
        ss += a * a + b * b;
    }
    ss += __shfl_xor(ss, 32); ss += __shfl_xor(ss, 16); ss += __shfl_xor(ss, 8);
    ss += __shfl_xor(ss, 4);  ss += __shfl_xor(ss, 2);  ss += __shfl_xor(ss, 1);
    __shared__ float red[4];
    if (lane == 0) red[wid] = ss;
    __syncthreads();
    float tot = red[0] + red[1] + red[2] + red[3];
    float sc = rsqrtf(tot * (1.0f / 1536.0f) + 1e-6f);

    #pragma unroll
    for (int q = 0; q < 3; ++q) {
        int p = t + q * 256;               // global pair index 0..767
        int ph = p & 63;                   // pair-in-head
        float fr = freqs[s * 128 + ph * 2];
        float fi = freqs[s * 128 + ph * 2 + 1];
        float nr = pr[q] * sc * g[2 * p];
        float ni = pi[q] * sc * g[2 * p + 1];
        float outr = nr * fr - ni * fi;
        float outi = nr * fi + ni * fr;
        row[p] = (unsigned int)f2bf(outr) | ((unsigned int)f2bf(outi) << 16);
    }
}

// ---------------------------------------------------------------- V transpose: [B,S,H,HD] -> [B*H, HD, S]
__global__ __launch_bounds__(256)
void vtrans(const unsigned short* __restrict__ V, unsigned short* __restrict__ Vt)
{
    __shared__ unsigned short tile[64][72];   // +8 pad
    const int s0 = blockIdx.x * 64;
    const int d0 = blockIdx.y * 64;
    const int bh = blockIdx.z;
    const int b = bh / HQ, h = bh % HQ;
    const int t = threadIdx.x;

    #pragma unroll
    for (int i = 0; i < 2; ++i) {
        int cid = i * 256 + t;
        int r = cid >> 3, c = cid & 7;
        u16x8 v = *(const u16x8*)(V + (size_t)(b * SQ + s0 + r) * DIMQ + h * HDQ + d0 + c * 8);
        #pragma unroll
        for (int e = 0; e < 8; ++e) tile[r][c * 8 + e] = v[e];
    }
    __syncthreads();
    #pragma unroll
    for (int i = 0; i < 2; ++i) {
        int cid = i * 256 + t;
        int rd = cid >> 3, c = cid & 7;
        u16x8 w;
        #pragma unroll
        for (int e = 0; e < 8; ++e) w[e] = tile[c * 8 + e][rd];
        *(u16x8*)(Vt + (size_t)(bh * HDQ + d0 + rd) * SQ + s0 + c * 8) = w;
    }
}

// ---------------------------------------------------------------- flash attention, 32x32 swapped
// Block = 2 waves x 32 q-rows = 64 q-rows. KVBLK=64.
// Swapped QK^T: sacc = mfma(K, Q) -> lane owns one q-col (lane&31), kv rows in regs.
// In-register softmax (raw-score units; scale folded into exp).
// P->bf16 B-frags via cvt_pk + __shfl_xor(32) + select (proven primitives).
// PV computes O^T = mfma(V^T, P^T) so softmax state stays lane-local.
__global__ __launch_bounds__(128)
void attn(const unsigned short* __restrict__ Q,
          const unsigned short* __restrict__ Kb,
          const unsigned short* __restrict__ Vt,
          unsigned short* __restrict__ Ao)
{
    __shared__ char smem[32768];
    char* Kl = smem;            // [64 kv][128 k] bf16, 256B rows, XOR-swizzled 16B chunks
    char* Vl = smem + 16384;    // [128 d][64 kv] bf16 (d-major), 128B rows, XOR-swizzled

    // XCD-aware remap: 8 XCDs x 3 heads x 32 s-blocks (per-head K/V ~1MB -> 3MB/XCD fits L2)
    const int fid = blockIdx.x;             // 0..767
    const int xcd = fid & 7;
    const int slot = fid >> 3;              // 0..95
    const int bh = xcd * 3 + (slot >> 5);   // 0..23
    const int sblk = slot & 31;
    const int b = bh / HQ, h = bh % HQ;
    const int s0 = sblk * 64;

    const int t = threadIdx.x;
    const int lane = t & 63, wid = t >> 6;
    const int l31 = lane & 31, hi = lane >> 5;
    const float scale = 0.08838834764831845f;   // 1/sqrt(128)
    const float THR = 90.5f;                    // 8/scale, raw-score units

    // Q fragments in registers (raw bf16; scale applied inside softmax exp).
    // B-frag for 32x32x16: col = q = lane&31, k = hi*8 + e.
    short8 qf[8];
    {
        const int qrow = b * SQ + s0 + wid * 32 + l31;
        const unsigned short* qp = Q + (size_t)qrow * DIMQ + h * HDQ;
        #pragma unroll
        for (int kc = 0; kc < 8; ++kc)
            qf[kc] = *(const short8*)(qp + kc * 16 + hi * 8);
    }

    float mrun = -1e30f, lsum = 0.f;
    f32x16 oacc[4] = {};   // O^T: col q = lane&31, row d = dt*32 + crow(r,hi)

    const unsigned short* Kbase = Kb + (size_t)(b * SQ) * DIMQ + h * HDQ;
    const unsigned short* Vbase = Vt + (size_t)(bh * HDQ) * SQ;

    #pragma unroll 1
    for (int kv0 = 0; kv0 < SQ; kv0 += 64) {
        // ---- stage K [64][128] and V^T [128][64]; 128 threads x 16B x 8 calls each
        #pragma unroll
        for (int i = 0; i < 8; ++i) {
            const int off = i * 2048 + t * 16;
            {   // K rows 256B = 16 chunks
                int r = off >> 8;
                int c = (off >> 4) & 15;
                gload_lds16(Kbase + (size_t)(kv0 + r) * DIMQ + ((c ^ (r & 7)) << 3),
                            Kl + i * 2048 + wid * 1024);
            }
            {   // Vt rows 128B = 8 chunks
                int r = off >> 7;
                int c = (off >> 4) & 7;
                gload_lds16(Vbase + (size_t)r * SQ + kv0 + ((c ^ (r & 7)) << 3),
                            Vl + i * 2048 + wid * 1024);
            }
        }
        __syncthreads();

        // ---- S^T = K * Q^T : D[kv][q], col q = lane&31, row kv = crow(r,hi) + 32*kvt
        f32x16 sacc[2] = {};
        #pragma unroll
        for (int kvt = 0; kvt < 2; ++kvt) {
            const int krow = kvt * 32 + l31;
            const int rb = krow * 256;
            #pragma unroll
            for (int kc = 0; kc < 8; ++kc) {
                int ch = (kc * 2 + hi) ^ (krow & 7);
                short8 kf = *(const short8*)(Kl + rb + ch * 16);
                sacc[kvt] = __builtin_amdgcn_mfma_f32_32x32x16_bf16(kf, qf[kc], sacc[kvt], 0, 0, 0);
            }
        }

        // ---- online softmax (raw-score units; lane holds 32 of 64 kv, partner lane^32 the rest)
        float tm = sacc[0][0];
        #pragma unroll
        for (int r = 1; r < 16; ++r) tm = fmaxf(tm, sacc[0][r]);
        #pragma unroll
        for (int r = 0; r < 16; ++r) tm = fmaxf(tm, sacc[1][r]);
        tm = fmaxf(tm, __shfl_xor(tm, 32));             // cross-half max
        if (!__all(tm <= mrun + THR)) {                 // defer-max (T13)
            float mnew = fmaxf(mrun, tm);
            float al = __expf((mrun - mnew) * scale);
            lsum *= al;
            #pragma unroll
            for (int dt = 0; dt < 4; ++dt)
                #pragma unroll
                for (int r = 0; r < 16; ++r) oacc[dt][r] *= al;
            mrun = mnew;
        }
        float rs = 0.f;
        #pragma unroll
        for (int kvt = 0; kvt < 2; ++kvt)
            #pragma unroll
            for (int r = 0; r < 16; ++r) {
                float p = __expf((sacc[kvt][r] - mrun) * scale);
                sacc[kvt][r] = p;
                rs += p;
            }
        rs += __shfl_xor(rs, 32);                       // cross-half sum
        lsum += rs;

        // ---- P -> bf16 B-frags + PV.
        // Lane's own P regs: a0/a1 = kv base+4hi+{0,1}/{2,3}; b0/b1 = base+8+4hi+{0,1}/{2,3}.
        // Word w of frag ks needs kv = ks*16 + hi*8 + {2w,2w+1}:
        //   w0 = hi ? partner(b0) : a0 ; w1 = hi ? partner(b1) : a1
        //   w2 = hi ? b0 : partner(a0) ; w3 = hi ? b1 : partner(a1)
        #pragma unroll
        for (int ks = 0; ks < 4; ++ks) {
            const int g = ks * 8;
            #define SV(f) (sacc[(f) >> 4][(f) & 15])
            unsigned int a0 = cvtpk_bf16(SV(g + 0), SV(g + 1));
            unsigned int a1 = cvtpk_bf16(SV(g + 2), SV(g + 3));
            unsigned int b0 = cvtpk_bf16(SV(g + 4), SV(g + 5));
            unsigned int b1 = cvtpk_bf16(SV(g + 6), SV(g + 7));
            #undef SV
            unsigned int xa0 = __shfl_xor(a0, 32);
            unsigned int xa1 = __shfl_xor(a1, 32);
            unsigned int xb0 = __shfl_xor(b0, 32);
            unsigned int xb1 = __shfl_xor(b1, 32);
            union { unsigned int w[4]; short8 v; } pf;
            pf.w[0] = hi ? xb0 : a0;
            pf.w[1] = hi ? xb1 : a1;
            pf.w[2] = hi ? b0 : xa0;
            pf.w[3] = hi ? b1 : xa1;
            #pragma unroll
            for (int dt = 0; dt < 4; ++dt) {
                const int drow = dt * 32 + l31;
                int ch = (ks * 2 + hi) ^ (drow & 7);
                short8 vf = *(const short8*)(Vl + drow * 128 + ch * 16);
                oacc[dt] = __builtin_amdgcn_mfma_f32_32x32x16_bf16(vf, pf.v, oacc[dt], 0, 0, 0);
            }
        }
        __syncthreads();
    }

    // ---- epilogue: normalize, transpose O^T -> O via wave-private swizzled LDS, store bf16
    const float rls = 1.0f / lsum;
    char* Ot = smem + wid * 8192;       // [32 q][128 d] bf16, 256B rows, XOR-swizzled
    #pragma unroll
    for (int dt = 0; dt < 4; ++dt)
        #pragma unroll
        for (int rp = 0; rp < 8; ++rp) {
            const int r = 2 * rp;
            float v0 = oacc[dt][r] * rls;
            float v1 = oacc[dt][r + 1] * rls;
            int d = dt * 32 + (r & 3) + 8 * (r >> 2) + 4 * hi;   // even
            unsigned int w = (unsigned int)f2bf(v0) | ((unsigned int)f2bf(v1) << 16);
            int addr = l31 * 256 + (((d >> 3) ^ (l31 & 7)) << 4) + (d & 7) * 2;
            *(unsigned int*)(Ot + addr) = w;
        }
    // wave-private region: same-wave RAW through LDS (compiler inserts lgkmcnt)
    #pragma unroll
    for (int ii = 0; ii < 8; ++ii) {
        int task = ii * 64 + lane;          // 32 q x 16 chunks
        int q = task >> 4, c = task & 15;
        u16x8 vv = *(const u16x8*)(Ot + q * 256 + ((c ^ (q & 7)) << 4));
        int tok = b * SQ + s0 + wid * 32 + q;
        *(u16x8*)(Ao + (size_t)tok * DIMQ + h * HDQ + c * 8) = vv;
    }
}

// ---------------------------------------------------------------- launch
extern "C" void kernel_launch(void* const* d_in, const int* in_sizes, int n_in,
                              void* d_out, int out_size, void* d_ws, size_t ws_size,
                              hipStream_t stream) {
    (void)in_sizes; (void)n_in; (void)out_size; (void)ws_size;
    const float* x     = (const float*)d_in[0];
    const float* freqs = (const float*)d_in[1];
    const float* wq = (const float*)d_in[2];
    const float* bq = (const float*)d_in[3];
    const float* wk = (const float*)d_in[4];
    const float* bk = (const float*)d_in[5];
    const float* wv = (const float*)d_in[6];
    const float* bv = (const float*)d_in[7];
    const float* wo = (const float*)d_in[8];
    const float* bo = (const float*)d_in[9];
    const float* gq = (const float*)d_in[10];
    const float* gk = (const float*)d_in[11];
    float* out = (float*)d_out;

    char* w = (char*)d_ws;
    unsigned short* Xb   = (unsigned short*)(w);               // 4096x1536 bf16
    unsigned short* Wqkv = (unsigned short*)(w + 12582912);    // 4608x1536 bf16
    unsigned short* Wob  = (unsigned short*)(w + 26738688);    // 1536x1536 bf16
    unsigned short* Qb   = (unsigned short*)(w + 31457280);    // 4096x1536 bf16
    unsigned short* Kbuf = (unsigned short*)(w + 44040192);    // 4096x1536 bf16
    unsigned short* Vb   = (unsigned short*)(w + 56623104);    // 4096x1536 bf16
    unsigned short* Vt   = (unsigned short*)(w + 69206016);    // 24x128x2048 bf16
    unsigned short* Ao   = Xb;   // Xb dead after GEMM1 -> reuse for attention out

    cast_f32_bf16<<<2048, 256, 0, stream>>>(x,  Xb,            6291456 / 4);
    cast_f32_bf16<<<1024, 256, 0, stream>>>(wq, Wqkv,          2359296 / 4);
    cast_f32_bf16<<<1024, 256, 0, stream>>>(wk, Wqkv + 2359296, 2359296 / 4);
    cast_f32_bf16<<<1024, 256, 0, stream>>>(wv, Wqkv + 4718592, 2359296 / 4);
    cast_f32_bf16<<<1024, 256, 0, stream>>>(wo, Wob,           2359296 / 4);

    gemm_bt<0><<<dim3(32, 36), 256, 0, stream>>>(
        Xb, Wqkv, Qb, Kbuf, Vb, bq, bk, bv, nullptr, nullptr);

    rmsnorm_rope<<<4096, 256, 0, stream>>>(Qb,   gq, freqs);
    rmsnorm_rope<<<4096, 256, 0, stream>>>(Kbuf, gk, freqs);
    vtrans<<<dim3(32, 2, 24), 256, 0, stream>>>(Vb, Vt);

    attn<<<768, 128, 0, stream>>>(Qb, Kbuf, Vt, Ao);

    gemm_bt<1><<<dim3(32, 12), 256, 0, stream>>>(
        Ao, Wob, nullptr, nullptr, nullptr, nullptr, nullptr, nullptr, out, bo);
}

// Round 4
// 277.880 us; speedup vs baseline: 1.1074x; 1.0197x over previous
//
#include <hip/hip_runtime.h>
#include <hip/hip_bf16.h>

// Problem: B=2, S=2048, DIM=1536, H=12, HD=128
//   q = rope(rms(x@wq.T + bq, gq)); k likewise; v = x@wv.T + bv
//   attn per head, out = attn_out @ wo.T + bo   (all fp32 reference)
// Strategy: bf16 MFMA pipeline (threshold = 2% of ref max, plenty of headroom).

#define BQ  2
#define SQ  2048
#define DIMQ 1536
#define HQ  12
#define HDQ 128
#define MTOK 4096          // B*S
#define KDIM 1536

typedef __attribute__((ext_vector_type(8))) short short8;   // 8 x bf16 (4 VGPR)
typedef __attribute__((ext_vector_type(4))) float f32x4;
typedef __attribute__((ext_vector_type(16))) float f32x16;
typedef __attribute__((ext_vector_type(8))) unsigned short u16x8;

typedef __attribute__((address_space(1))) const void global_cvoid;
typedef __attribute__((address_space(3))) void lds_void;

__device__ __forceinline__ float bf2f(unsigned int u) {
    return __uint_as_float(u << 16);
}
__device__ __forceinline__ unsigned short f2bf(float f) {
    unsigned int u = __float_as_uint(f);
    u += 0x7fffu + ((u >> 16) & 1u);   // round-to-nearest-even
    return (unsigned short)(u >> 16);
}
__device__ __forceinline__ void gload_lds16(const void* g, void* l) {
    __builtin_amdgcn_global_load_lds((global_cvoid*)g, (lds_void*)l, 16, 0, 0);
}
__device__ __forceinline__ unsigned int cvtpk_bf16(float lo, float hi) {
    unsigned int r;
    asm("v_cvt_pk_bf16_f32 %0, %1, %2" : "=v"(r) : "v"(lo), "v"(hi));
    return r;
}

// counted vmcnt wait (T4): never drain to 0 in the main loop
#define VMCNT(n) asm volatile("s_waitcnt vmcnt(" #n ")" ::: "memory")
// raw barrier with compiler fences on both sides (no vmcnt/lgkmcnt drain)
#define BARRIER() do { asm volatile("" ::: "memory"); \
                       __builtin_amdgcn_s_barrier();  \
                       asm volatile("" ::: "memory"); } while (0)

// ---------------------------------------------------------------- fused casts f32->bf16
// segments: x (1572864 f4) -> Xb; wq,wk,wv (589824 f4 each) -> Wqkv; wo -> Wob
__global__ __launch_bounds__(256)
void cast_all(const float* __restrict__ x,
              const float* __restrict__ wq, const float* __restrict__ wk,
              const float* __restrict__ wv, const float* __restrict__ wo,
              unsigned short* __restrict__ Xb,
              unsigned short* __restrict__ Wqkv,
              unsigned short* __restrict__ Wob)
{
    const int NX = 1572864, NW = 589824;
    int i = blockIdx.x * blockDim.x + threadIdx.x;
    int stride = gridDim.x * blockDim.x;
    for (; i < NX + 4 * NW; i += stride) {
        const float* s; unsigned short* d; int off;
        if (i < NX) { s = x; d = Xb; off = i; }
        else {
            int j = i - NX;
            int seg = j / NW;
            off = j - seg * NW;
            s = (seg == 0) ? wq : (seg == 1) ? wk : (seg == 2) ? wv : wo;
            d = (seg < 3) ? (Wqkv + seg * 2359296) : Wob;
        }
        float4 v = ((const float4*)s)[off];
        unsigned short a = f2bf(v.x), b = f2bf(v.y), c = f2bf(v.z), e = f2bf(v.w);
        unsigned int lo = (unsigned int)a | ((unsigned int)b << 16);
        unsigned int hi = (unsigned int)c | ((unsigned int)e << 16);
        ((uint2*)d)[off] = make_uint2(lo, hi);
    }
}

// ---------------------------------------------------------------- GEMM C = A * B^T  (+bias)
// A: [M x 1536] bf16 row-major, Bm: [N x 1536] bf16 row-major (weight rows).
// MODE 0: N=4608 (q|k|v concat) -> bf16 out into oQ/oK/oV with per-segment bias.
// MODE 1: N=1536 -> fp32 out (d_out) + bias.
// 128x128 tile, BK=64, 4 waves (2x2 of 64x64), single-buffer LDS w/ XOR swizzle.
template<int MODE>
__global__ __launch_bounds__(256)
void gemm_bt(const unsigned short* __restrict__ A,
             const unsigned short* __restrict__ Bm,
             unsigned short* __restrict__ oQ,
             unsigned short* __restrict__ oK,
             unsigned short* __restrict__ oV,
             const float* __restrict__ biasq,
             const float* __restrict__ biask,
             const float* __restrict__ biasv,
             float* __restrict__ oF,
             const float* __restrict__ biaso)
{
    __shared__ unsigned short ldsA[128 * 64];   // 16 KB
    __shared__ unsigned short ldsB[128 * 64];   // 16 KB
    const int m0 = blockIdx.x * 128;
    const int n0 = blockIdx.y * 128;
    const int t = threadIdx.x;
    const int lane = t & 63;
    const int wid = t >> 6;
    const int wr = (wid >> 1) * 64;
    const int wc = (wid & 1) * 64;
    const int lr = lane & 15;
    const int lk = lane >> 4;

    f32x4 acc[4][4] = {};

    #pragma unroll 1
    for (int kt = 0; kt < KDIM; kt += 64) {
        #pragma unroll
        for (int i = 0; i < 4; ++i) {
            const int off = i * 4096 + wid * 1024 + lane * 16;  // byte offset in tile
            const int r = off >> 7;
            const int c = (off >> 4) & 7;
            const int csw = (c ^ (r & 7)) << 3;                 // element offset in row
            gload_lds16(A + (size_t)(m0 + r) * KDIM + kt + csw,
                        (char*)ldsA + i * 4096 + wid * 1024);
            gload_lds16(Bm + (size_t)(n0 + r) * KDIM + kt + csw,
                        (char*)ldsB + i * 4096 + wid * 1024);
        }
        __syncthreads();

        #pragma unroll
        for (int kk = 0; kk < 2; ++kk) {
            short8 af[4], bf[4];
            #pragma unroll
            for (int mi = 0; mi < 4; ++mi) {
                int row = wr + mi * 16 + lr;
                int ch = (kk * 4 + lk) ^ (row & 7);
                af[mi] = *(const short8*)((const char*)ldsA + row * 128 + ch * 16);
            }
            #pragma unroll
            for (int ni = 0; ni < 4; ++ni) {
                int row = wc + ni * 16 + lr;
                int ch = (kk * 4 + lk) ^ (row & 7);
                bf[ni] = *(const short8*)((const char*)ldsB + row * 128 + ch * 16);
            }
            #pragma unroll
            for (int mi = 0; mi < 4; ++mi)
                #pragma unroll
                for (int ni = 0; ni < 4; ++ni)
                    acc[mi][ni] = __builtin_amdgcn_mfma_f32_16x16x32_bf16(
                        af[mi], bf[ni], acc[mi][ni], 0, 0, 0);
        }
        __syncthreads();
    }

    // epilogue: D layout col=lane&15, row=(lane>>4)*4+j  [m89-verified]
    if (MODE == 0) {
        const int seg = n0 / 1536;
        unsigned short* op = (seg == 0) ? oQ : (seg == 1 ? oK : oV);
        const float* bp = (seg == 0) ? biasq : (seg == 1 ? biask : biasv);
        const int nl0 = n0 - seg * 1536;
        #pragma unroll
        for (int mi = 0; mi < 4; ++mi)
            #pragma unroll
            for (int ni = 0; ni < 4; ++ni)
                #pragma unroll
                for (int j = 0; j < 4; ++j) {
                    int row = m0 + wr + mi * 16 + lk * 4 + j;
                    int col = nl0 + wc + ni * 16 + lr;
                    op[(size_t)row * 1536 + col] = f2bf(acc[mi][ni][j] + bp[col]);
                }
    } else {
        #pragma unroll
        for (int mi = 0; mi < 4; ++mi)
            #pragma unroll
            for (int ni = 0; ni < 4; ++ni)
                #pragma unroll
                for (int j = 0; j < 4; ++j) {
                    int row = m0 + wr + mi * 16 + lk * 4 + j;
                    int col = n0 + wc + ni * 16 + lr;
                    oF[(size_t)row * 1536 + col] = acc[mi][ni][j] + biaso[col];
                }
    }
}

// ---------------------------------------------------------------- RMSNorm (full row) + RoPE, in place
__global__ __launch_bounds__(256)
void rmsnorm_rope(unsigned short* __restrict__ T,
                  const float* __restrict__ g,
                  const float* __restrict__ freqs)
{
    const int token = blockIdx.x;          // 0..4095
    const int s = token & (SQ - 1);
    unsigned int* row = (unsigned int*)(T + (size_t)token * DIMQ);
    const int t = threadIdx.x;
    const int lane = t & 63, wid = t >> 6;

    float pr[3], pi[3];
    float ss = 0.f;
    #pragma unroll
    for (int q = 0; q < 3; ++q) {
        unsigned int v = row[t + q * 256];
        float a = bf2f(v & 0xffffu);
        float b = bf2f(v >> 16);
        pr[q] = a; pi[q] = b;
        ss += a * a + b * b;
    }
    ss += __shfl_xor(ss, 32); ss += __shfl_xor(ss, 16); ss += __shfl_xor(ss, 8);
    ss += __shfl_xor(ss, 4);  ss += __shfl_xor(ss, 2);  ss += __shfl_xor(ss, 1);
    __shared__ float red[4];
    if (lane == 0) red[wid] = ss;
    __syncthreads();
    float tot = red[0] + red[1] + red[2] + red[3];
    float sc = rsqrtf(tot * (1.0f / 1536.0f) + 1e-6f);

    #pragma unroll
    for (int q = 0; q < 3; ++q) {
        int p = t + q * 256;               // global pair index 0..767
        int ph = p & 63;                   // pair-in-head
        float fr = freqs[s * 128 + ph * 2];
        float fi = freqs[s * 128 + ph * 2 + 1];
        float nr = pr[q] * sc * g[2 * p];
        float ni = pi[q] * sc * g[2 * p + 1];
        float outr = nr * fr - ni * fi;
        float outi = nr * fi + ni * fr;
        row[p] = (unsigned int)f2bf(outr) | ((unsigned int)f2bf(outi) << 16);
    }
}

// ---------------------------------------------------------------- V transpose: [B,S,H,HD] -> [B*H, HD, S]
__global__ __launch_bounds__(256)
void vtrans(const unsigned short* __restrict__ V, unsigned short* __restrict__ Vt)
{
    __shared__ unsigned short tile[64][72];   // +8 pad
    const int s0 = blockIdx.x * 64;
    const int d0 = blockIdx.y * 64;
    const int bh = blockIdx.z;
    const int b = bh / HQ, h = bh % HQ;
    const int t = threadIdx.x;

    #pragma unroll
    for (int i = 0; i < 2; ++i) {
        int cid = i * 256 + t;
        int r = cid >> 3, c = cid & 7;
        u16x8 v = *(const u16x8*)(V + (size_t)(b * SQ + s0 + r) * DIMQ + h * HDQ + d0 + c * 8);
        #pragma unroll
        for (int e = 0; e < 8; ++e) tile[r][c * 8 + e] = v[e];
    }
    __syncthreads();
    #pragma unroll
    for (int i = 0; i < 2; ++i) {
        int cid = i * 256 + t;
        int rd = cid >> 3, c = cid & 7;
        u16x8 w;
        #pragma unroll
        for (int e = 0; e < 8; ++e) w[e] = tile[c * 8 + e][rd];
        *(u16x8*)(Vt + (size_t)(bh * HDQ + d0 + rd) * SQ + s0 + c * 8) = w;
    }
}

// ---------------------------------------------------------------- flash attention, 32x32 swapped, pipelined
// Block = 2 waves x 32 q-rows = 64 q-rows. KVBLK=64.
// T3/T4: K double-buffered with 1-tile prefetch, V single-buffered (issued early,
// consumed after QK^T+softmax); counted vmcnt (16/8), raw barriers (3/iter).
// Swapped QK^T: sacc = mfma(K, Q); in-register softmax; P via cvt_pk + shfl+select;
// PV computes O^T = mfma(V^T, P^T). T5 setprio around MFMA clusters.
__global__ __launch_bounds__(128)
void attn(const unsigned short* __restrict__ Q,
          const unsigned short* __restrict__ Kb,
          const unsigned short* __restrict__ Vt,
          unsigned short* __restrict__ Ao)
{
    __shared__ char smem[49152];
    char* Kl0 = smem;            // K dbuf: [64 kv][128 k] bf16, 256B rows, swizzled
    char* Kl1 = smem + 16384;
    char* Vl  = smem + 32768;    // V: [128 d][64 kv] bf16, 128B rows, swizzled

    // XCD-aware remap: 8 XCDs x 3 heads x 32 s-blocks (3MB K/V per XCD fits L2)
    const int fid = blockIdx.x;             // 0..767
    const int xcd = fid & 7;
    const int slot = fid >> 3;              // 0..95
    const int bh = xcd * 3 + (slot >> 5);   // 0..23
    const int sblk = slot & 31;
    const int b = bh / HQ, h = bh % HQ;
    const int s0 = sblk * 64;

    const int t = threadIdx.x;
    const int lane = t & 63, wid = t >> 6;
    const int l31 = lane & 31, hi = lane >> 5;
    const float THR = 90.5f;                     // 8/scale, raw-score units
    const float CE = 0.12751879f;                // scale * log2(e); exp(x*s) = exp2(x*CE)

    const unsigned short* Kbase = Kb + (size_t)(b * SQ) * DIMQ + h * HDQ;
    const unsigned short* Vbase = Vt + (size_t)(bh * HDQ) * SQ;

    // Q fragments in registers (raw bf16; scale folded into exp2 constant).
    short8 qf[8];
    {
        const int qrow = b * SQ + s0 + wid * 32 + l31;
        const unsigned short* qp = Q + (size_t)qrow * DIMQ + h * HDQ;
        #pragma unroll
        for (int kc = 0; kc < 8; ++kc)
            qf[kc] = *(const short8*)(qp + kc * 16 + hi * 8);
    }

    float mrun = -1e30f, lsum = 0.f;
    f32x16 oacc[4] = {};   // O^T: col q = lane&31, row d = dt*32 + crow(r,hi)

    // ---- prologue: stage K(0) into Kl0  [8 gload_lds per wave]
    #pragma unroll
    for (int i = 0; i < 8; ++i) {
        const int off = i * 2048 + t * 16;
        int r = off >> 8, c = (off >> 4) & 15;
        gload_lds16(Kbase + (size_t)r * DIMQ + ((c ^ (r & 7)) << 3),
                    Kl0 + i * 2048 + wid * 1024);
    }

    char* kcur = Kl0;
    char* knxt = Kl1;

    #pragma unroll 1
    for (int kv0 = 0; kv0 < SQ; kv0 += 64) {
        // ---- issue V(t) [8], then K(t+1) [8] (clamped in-bounds); order pinned
        #pragma unroll
        for (int i = 0; i < 8; ++i) {
            const int off = i * 2048 + t * 16;
            int r = off >> 7, c = (off >> 4) & 7;
            gload_lds16(Vbase + (size_t)r * SQ + kv0 + ((c ^ (r & 7)) << 3),
                        Vl + i * 2048 + wid * 1024);
        }
        asm volatile("" ::: "memory");
        const int kvn = (kv0 + 64 < SQ) ? kv0 + 64 : kv0;   // clamp last prefetch
        #pragma unroll
        for (int i = 0; i < 8; ++i) {
            const int off = i * 2048 + t * 16;
            int r = off >> 8, c = (off >> 4) & 15;
            gload_lds16(Kbase + (size_t)(kvn + r) * DIMQ + ((c ^ (r & 7)) << 3),
                        knxt + i * 2048 + wid * 1024);
        }

        VMCNT(16);          // oldest 8 (K(t)) landed; V(t)+K(t+1) still in flight
        BARRIER();          // #1: K(t) visible block-wide

        // ---- S^T = K * Q^T : D[kv][q], col q = lane&31, row kv = crow(r,hi) + 32*kvt
        f32x16 sacc[2] = {};
        __builtin_amdgcn_s_setprio(1);
        #pragma unroll
        for (int kvt = 0; kvt < 2; ++kvt) {
            const int krow = kvt * 32 + l31;
            const int rb = krow * 256;
            #pragma unroll
            for (int kc = 0; kc < 8; ++kc) {
                int ch = (kc * 2 + hi) ^ (krow & 7);
                short8 kf = *(const short8*)(kcur + rb + ch * 16);
                sacc[kvt] = __builtin_amdgcn_mfma_f32_32x32x16_bf16(kf, qf[kc], sacc[kvt], 0, 0, 0);
            }
        }
        __builtin_amdgcn_s_setprio(0);

        // ---- online softmax (raw-score units; lane holds 32 of 64 kv; partner lane^32 rest)
        float mt[16];
        #pragma unroll
        for (int r = 0; r < 16; ++r) mt[r] = fmaxf(sacc[0][r], sacc[1][r]);
        #pragma unroll
        for (int s = 8; s > 0; s >>= 1)
            #pragma unroll
            for (int r = 0; r < 8; ++r)
                if (r < s) mt[r] = fmaxf(mt[r], mt[r + s]);
        float tm = mt[0];
        tm = fmaxf(tm, __shfl_xor(tm, 32));             // cross-half max
        if (!__all(tm <= mrun + THR)) {                 // defer-max (T13)
            float mnew = fmaxf(mrun, tm);
            float al = __builtin_amdgcn_exp2f((mrun - mnew) * CE);
            lsum *= al;
            #pragma unroll
            for (int dt = 0; dt < 4; ++dt)
                #pragma unroll
                for (int r = 0; r < 16; ++r) oacc[dt][r] *= al;
            mrun = mnew;
        }
        float rs = 0.f;
        #pragma unroll
        for (int kvt = 0; kvt < 2; ++kvt)
            #pragma unroll
            for (int r = 0; r < 16; ++r) {
                float p = __builtin_amdgcn_exp2f((sacc[kvt][r] - mrun) * CE);
                sacc[kvt][r] = p;
                rs += p;
            }
        rs += __shfl_xor(rs, 32);                       // cross-half sum
        lsum += rs;

        VMCNT(8);           // V(t) landed; K(t+1) still in flight
        BARRIER();          // #2: V(t) visible block-wide

        // ---- P -> bf16 B-frags + PV (O^T += V^T P^T)
        __builtin_amdgcn_s_setprio(1);
        #pragma unroll
        for (int ks = 0; ks < 4; ++ks) {
            const int g = ks * 8;
            #define SV(f) (sacc[(f) >> 4][(f) & 15])
            unsigned int a0 = cvtpk_bf16(SV(g + 0), SV(g + 1));
            unsigned int a1 = cvtpk_bf16(SV(g + 2), SV(g + 3));
            unsigned int b0 = cvtpk_bf16(SV(g + 4), SV(g + 5));
            unsigned int b1 = cvtpk_bf16(SV(g + 6), SV(g + 7));
            #undef SV
            unsigned int xa0 = __shfl_xor(a0, 32);
            unsigned int xa1 = __shfl_xor(a1, 32);
            unsigned int xb0 = __shfl_xor(b0, 32);
            unsigned int xb1 = __shfl_xor(b1, 32);
            union { unsigned int w[4]; short8 v; } pf;
            pf.w[0] = hi ? xb0 : a0;
            pf.w[1] = hi ? xb1 : a1;
            pf.w[2] = hi ? b0 : xa0;
            pf.w[3] = hi ? b1 : xa1;
            #pragma unroll
            for (int dt = 0; dt < 4; ++dt) {
                const int drow = dt * 32 + l31;
                int ch = (ks * 2 + hi) ^ (drow & 7);
                short8 vf = *(const short8*)(Vl + drow * 128 + ch * 16);
                oacc[dt] = __builtin_amdgcn_mfma_f32_32x32x16_bf16(vf, pf.v, oacc[dt], 0, 0, 0);
            }
        }
        __builtin_amdgcn_s_setprio(0);

        BARRIER();          // #3: all waves done reading Vl/kcur -> next iter may overwrite

        char* tmp = kcur; kcur = knxt; knxt = tmp;
    }

    // ---- epilogue: normalize, transpose O^T -> O via wave-private swizzled LDS (V region:
    // safe — only K-prefetch DMA is still in flight, and it targets the K buffers)
    const float rls = 1.0f / lsum;
    char* Ot = smem + 32768 + wid * 8192;   // [32 q][128 d] bf16 wave-half, swizzled
    #pragma unroll
    for (int dt = 0; dt < 4; ++dt)
        #pragma unroll
        for (int rp = 0; rp < 8; ++rp) {
            const int r = 2 * rp;
            float v0 = oacc[dt][r] * rls;
            float v1 = oacc[dt][r + 1] * rls;
            int d = dt * 32 + (r & 3) + 8 * (r >> 2) + 4 * hi;   // even
            unsigned int w = (unsigned int)f2bf(v0) | ((unsigned int)f2bf(v1) << 16);
            int addr = l31 * 256 + (((d >> 3) ^ (l31 & 7)) << 4) + (d & 7) * 2;
            *(unsigned int*)(Ot + addr) = w;
        }
    // wave-private region: same-wave RAW through LDS (compiler inserts lgkmcnt)
    #pragma unroll
    for (int ii = 0; ii < 8; ++ii) {
        int task = ii * 64 + lane;          // 32 q x 16 chunks
        int q = task >> 4, c = task & 15;
        u16x8 vv = *(const u16x8*)(Ot + q * 256 + ((c ^ (q & 7)) << 4));
        int tok = b * SQ + s0 + wid * 32 + q;
        *(u16x8*)(Ao + (size_t)tok * DIMQ + h * HDQ + c * 8) = vv;
    }
}

// ---------------------------------------------------------------- launch
extern "C" void kernel_launch(void* const* d_in, const int* in_sizes, int n_in,
                              void* d_out, int out_size, void* d_ws, size_t ws_size,
                              hipStream_t stream) {
    (void)in_sizes; (void)n_in; (void)out_size; (void)ws_size;
    const float* x     = (const float*)d_in[0];
    const float* freqs = (const float*)d_in[1];
    const float* wq = (const float*)d_in[2];
    const float* bq = (const float*)d_in[3];
    const float* wk = (const float*)d_in[4];
    const float* bk = (const float*)d_in[5];
    const float* wv = (const float*)d_in[6];
    const float* bv = (const float*)d_in[7];
    const float* wo = (const float*)d_in[8];
    const float* bo = (const float*)d_in[9];
    const float* gq = (const float*)d_in[10];
    const float* gk = (const float*)d_in[11];
    float* out = (float*)d_out;

    char* w = (char*)d_ws;
    unsigned short* Xb   = (unsigned short*)(w);               // 4096x1536 bf16
    unsigned short* Wqkv = (unsigned short*)(w + 12582912);    // 4608x1536 bf16
    unsigned short* Wob  = (unsigned short*)(w + 26738688);    // 1536x1536 bf16
    unsigned short* Qb   = (unsigned short*)(w + 31457280);    // 4096x1536 bf16
    unsigned short* Kbuf = (unsigned short*)(w + 44040192);    // 4096x1536 bf16
    unsigned short* Vb   = (unsigned short*)(w + 56623104);    // 4096x1536 bf16
    unsigned short* Vt   = (unsigned short*)(w + 69206016);    // 24x128x2048 bf16
    unsigned short* Ao   = Xb;   // Xb dead after GEMM1 -> reuse for attention out

    cast_all<<<2048, 256, 0, stream>>>(x, wq, wk, wv, wo, Xb, Wqkv, Wob);

    gemm_bt<0><<<dim3(32, 36), 256, 0, stream>>>(
        Xb, Wqkv, Qb, Kbuf, Vb, bq, bk, bv, nullptr, nullptr);

    rmsnorm_rope<<<4096, 256, 0, stream>>>(Qb,   gq, freqs);
    rmsnorm_rope<<<4096, 256, 0, stream>>>(Kbuf, gk, freqs);
    vtrans<<<dim3(32, 2, 24), 256, 0, stream>>>(Vb, Vt);

    attn<<<768, 128, 0, stream>>>(Qb, Kbuf, Vt, Ao);

    gemm_bt<1><<<dim3(32, 12), 256, 0, stream>>>(
        Ao, Wob, nullptr, nullptr, nullptr, nullptr, nullptr, nullptr, out, bo);
}

// Round 5
// 255.439 us; speedup vs baseline: 1.2047x; 1.0879x over previous
//
#include <hip/hip_runtime.h>
#include <hip/hip_bf16.h>

// Problem: B=2, S=2048, DIM=1536, H=12, HD=128
//   q = rope(rms(x@wq.T + bq, gq)); k likewise; v = x@wv.T + bv
//   attn per head, out = attn_out @ wo.T + bo   (all fp32 reference)
// Strategy: bf16 MFMA pipeline (threshold = 2% of ref max, plenty of headroom).

#define BQ  2
#define SQ  2048
#define DIMQ 1536
#define HQ  12
#define HDQ 128
#define MTOK 4096          // B*S
#define KDIM 1536

typedef __attribute__((ext_vector_type(8))) short short8;   // 8 x bf16 (4 VGPR)
typedef __attribute__((ext_vector_type(4))) float f32x4;
typedef __attribute__((ext_vector_type(16))) float f32x16;
typedef __attribute__((ext_vector_type(8))) unsigned short u16x8;

typedef __attribute__((address_space(1))) const void global_cvoid;
typedef __attribute__((address_space(3))) void lds_void;

__device__ __forceinline__ float bf2f(unsigned int u) {
    return __uint_as_float(u << 16);
}
__device__ __forceinline__ unsigned short f2bf(float f) {
    unsigned int u = __float_as_uint(f);
    u += 0x7fffu + ((u >> 16) & 1u);   // round-to-nearest-even
    return (unsigned short)(u >> 16);
}
__device__ __forceinline__ void gload_lds16(const void* g, void* l) {
    __builtin_amdgcn_global_load_lds((global_cvoid*)g, (lds_void*)l, 16, 0, 0);
}
__device__ __forceinline__ unsigned int cvtpk_bf16(float lo, float hi) {
    unsigned int r;
    asm("v_cvt_pk_bf16_f32 %0, %1, %2" : "=v"(r) : "v"(lo), "v"(hi));
    return r;
}

// counted vmcnt wait (T4): never drain to 0 in the main loop
#define VMCNT(n) asm volatile("s_waitcnt vmcnt(" #n ")" ::: "memory")
#define MEMFENCE() asm volatile("" ::: "memory")

// ---------------------------------------------------------------- fused casts f32->bf16
// segments: x (1572864 f4) -> Xb; wq,wk,wv (589824 f4 each) -> Wqkv; wo -> Wob
__global__ __launch_bounds__(256)
void cast_all(const float* __restrict__ x,
              const float* __restrict__ wq, const float* __restrict__ wk,
              const float* __restrict__ wv, const float* __restrict__ wo,
              unsigned short* __restrict__ Xb,
              unsigned short* __restrict__ Wqkv,
              unsigned short* __restrict__ Wob)
{
    const int NX = 1572864, NW = 589824;
    int i = blockIdx.x * blockDim.x + threadIdx.x;
    int stride = gridDim.x * blockDim.x;
    for (; i < NX + 4 * NW; i += stride) {
        const float* s; unsigned short* d; int off;
        if (i < NX) { s = x; d = Xb; off = i; }
        else {
            int j = i - NX;
            int seg = j / NW;
            off = j - seg * NW;
            s = (seg == 0) ? wq : (seg == 1) ? wk : (seg == 2) ? wv : wo;
            d = (seg < 3) ? (Wqkv + seg * 2359296) : Wob;
        }
        float4 v = ((const float4*)s)[off];
        unsigned short a = f2bf(v.x), b = f2bf(v.y), c = f2bf(v.z), e = f2bf(v.w);
        unsigned int lo = (unsigned int)a | ((unsigned int)b << 16);
        unsigned int hi = (unsigned int)c | ((unsigned int)e << 16);
        ((uint2*)d)[off] = make_uint2(lo, hi);
    }
}

// ---------------------------------------------------------------- GEMM C = A * B^T  (+bias)
// A: [M x 1536] bf16 row-major, Bm: [N x 1536] bf16 row-major (weight rows).
// MODE 0: N=4608 (q|k|v concat) -> bf16 out into oQ/oK/oV with per-segment bias.
// MODE 1: N=1536 -> fp32 out (d_out) + bias.
// 128x128 tile, BK=64, 4 waves (2x2 of 64x64), single-buffer LDS w/ XOR swizzle.
template<int MODE>
__global__ __launch_bounds__(256)
void gemm_bt(const unsigned short* __restrict__ A,
             const unsigned short* __restrict__ Bm,
             unsigned short* __restrict__ oQ,
             unsigned short* __restrict__ oK,
             unsigned short* __restrict__ oV,
             const float* __restrict__ biasq,
             const float* __restrict__ biask,
             const float* __restrict__ biasv,
             float* __restrict__ oF,
             const float* __restrict__ biaso)
{
    __shared__ unsigned short ldsA[128 * 64];   // 16 KB
    __shared__ unsigned short ldsB[128 * 64];   // 16 KB
    const int m0 = blockIdx.x * 128;
    const int n0 = blockIdx.y * 128;
    const int t = threadIdx.x;
    const int lane = t & 63;
    const int wid = t >> 6;
    const int wr = (wid >> 1) * 64;
    const int wc = (wid & 1) * 64;
    const int lr = lane & 15;
    const int lk = lane >> 4;

    f32x4 acc[4][4] = {};

    #pragma unroll 1
    for (int kt = 0; kt < KDIM; kt += 64) {
        #pragma unroll
        for (int i = 0; i < 4; ++i) {
            const int off = i * 4096 + wid * 1024 + lane * 16;  // byte offset in tile
            const int r = off >> 7;
            const int c = (off >> 4) & 7;
            const int csw = (c ^ (r & 7)) << 3;                 // element offset in row
            gload_lds16(A + (size_t)(m0 + r) * KDIM + kt + csw,
                        (char*)ldsA + i * 4096 + wid * 1024);
            gload_lds16(Bm + (size_t)(n0 + r) * KDIM + kt + csw,
                        (char*)ldsB + i * 4096 + wid * 1024);
        }
        __syncthreads();

        #pragma unroll
        for (int kk = 0; kk < 2; ++kk) {
            short8 af[4], bf[4];
            #pragma unroll
            for (int mi = 0; mi < 4; ++mi) {
                int row = wr + mi * 16 + lr;
                int ch = (kk * 4 + lk) ^ (row & 7);
                af[mi] = *(const short8*)((const char*)ldsA + row * 128 + ch * 16);
            }
            #pragma unroll
            for (int ni = 0; ni < 4; ++ni) {
                int row = wc + ni * 16 + lr;
                int ch = (kk * 4 + lk) ^ (row & 7);
                bf[ni] = *(const short8*)((const char*)ldsB + row * 128 + ch * 16);
            }
            #pragma unroll
            for (int mi = 0; mi < 4; ++mi)
                #pragma unroll
                for (int ni = 0; ni < 4; ++ni)
                    acc[mi][ni] = __builtin_amdgcn_mfma_f32_16x16x32_bf16(
                        af[mi], bf[ni], acc[mi][ni], 0, 0, 0);
        }
        __syncthreads();
    }

    // epilogue: D layout col=lane&15, row=(lane>>4)*4+j  [m89-verified]
    if (MODE == 0) {
        const int seg = n0 / 1536;
        unsigned short* op = (seg == 0) ? oQ : (seg == 1 ? oK : oV);
        const float* bp = (seg == 0) ? biasq : (seg == 1 ? biask : biasv);
        const int nl0 = n0 - seg * 1536;
        #pragma unroll
        for (int mi = 0; mi < 4; ++mi)
            #pragma unroll
            for (int ni = 0; ni < 4; ++ni)
                #pragma unroll
                for (int j = 0; j < 4; ++j) {
                    int row = m0 + wr + mi * 16 + lk * 4 + j;
                    int col = nl0 + wc + ni * 16 + lr;
                    op[(size_t)row * 1536 + col] = f2bf(acc[mi][ni][j] + bp[col]);
                }
    } else {
        #pragma unroll
        for (int mi = 0; mi < 4; ++mi)
            #pragma unroll
            for (int ni = 0; ni < 4; ++ni)
                #pragma unroll
                for (int j = 0; j < 4; ++j) {
                    int row = m0 + wr + mi * 16 + lk * 4 + j;
                    int col = n0 + wc + ni * 16 + lr;
                    oF[(size_t)row * 1536 + col] = acc[mi][ni][j] + biaso[col];
                }
    }
}

// ---------------------------------------------------------------- RMSNorm (full row) + RoPE, in place
__global__ __launch_bounds__(256)
void rmsnorm_rope(unsigned short* __restrict__ T,
                  const float* __restrict__ g,
                  const float* __restrict__ freqs)
{
    const int token = blockIdx.x;          // 0..4095
    const int s = token & (SQ - 1);
    unsigned int* row = (unsigned int*)(T + (size_t)token * DIMQ);
    const int t = threadIdx.x;
    const int lane = t & 63, wid = t >> 6;

    float pr[3], pi[3];
    float ss = 0.f;
    #pragma unroll
    for (int q = 0; q < 3; ++q) {
        unsigned int v = row[t + q * 256];
        float a = bf2f(v & 0xffffu);
        float b = bf2f(v >> 16);
        pr[q] = a; pi[q] = b;
        ss += a * a + b * b;
    }
    ss += __shfl_xor(ss, 32); ss += __shfl_xor(ss, 16); ss += __shfl_xor(ss, 8);
    ss += __shfl_xor(ss, 4);  ss += __shfl_xor(ss, 2);  ss += __shfl_xor(ss, 1);
    __shared__ float red[4];
    if (lane == 0) red[wid] = ss;
    __syncthreads();
    float tot = red[0] + red[1] + red[2] + red[3];
    float sc = rsqrtf(tot * (1.0f / 1536.0f) + 1e-6f);

    #pragma unroll
    for (int q = 0; q < 3; ++q) {
        int p = t + q * 256;               // global pair index 0..767
        int ph = p & 63;                   // pair-in-head
        float fr = freqs[s * 128 + ph * 2];
        float fi = freqs[s * 128 + ph * 2 + 1];
        float nr = pr[q] * sc * g[2 * p];
        float ni = pi[q] * sc * g[2 * p + 1];
        float outr = nr * fr - ni * fi;
        float outi = nr * fi + ni * fr;
        row[p] = (unsigned int)f2bf(outr) | ((unsigned int)f2bf(outi) << 16);
    }
}

// ---------------------------------------------------------------- V transpose: [B,S,H,HD] -> [B*H, HD, S]
__global__ __launch_bounds__(256)
void vtrans(const unsigned short* __restrict__ V, unsigned short* __restrict__ Vt)
{
    __shared__ unsigned short tile[64][72];   // +8 pad
    const int s0 = blockIdx.x * 64;
    const int d0 = blockIdx.y * 64;
    const int bh = blockIdx.z;
    const int b = bh / HQ, h = bh % HQ;
    const int t = threadIdx.x;

    #pragma unroll
    for (int i = 0; i < 2; ++i) {
        int cid = i * 256 + t;
        int r = cid >> 3, c = cid & 7;
        u16x8 v = *(const u16x8*)(V + (size_t)(b * SQ + s0 + r) * DIMQ + h * HDQ + d0 + c * 8);
        #pragma unroll
        for (int e = 0; e < 8; ++e) tile[r][c * 8 + e] = v[e];
    }
    __syncthreads();
    #pragma unroll
    for (int i = 0; i < 2; ++i) {
        int cid = i * 256 + t;
        int rd = cid >> 3, c = cid & 7;
        u16x8 w;
        #pragma unroll
        for (int e = 0; e < 8; ++e) w[e] = tile[c * 8 + e][rd];
        *(u16x8*)(Vt + (size_t)(bh * HDQ + d0 + rd) * SQ + s0 + c * 8) = w;
    }
}

// ---------------------------------------------------------------- flash attention
// 1 wave per block (64 threads), 32 q-rows, KVBLK=32, NO barriers (wave-private LDS).
// K double-buffered (2x8KB DMA) + V single (8KB, issued early); two counted vmcnts
// per iter (T4). Swapped QK^T = mfma(K,Q), lane-local online softmax, P via
// cvt_pk + shfl_xor(32) + select, PV computes O^T = mfma(V^T, P^T).
// Grid 1536 = 6 blocks/CU exactly; LDS 24KB -> 6 resident; VGPR capped 256.
__global__ __launch_bounds__(64, 2)
void attn(const unsigned short* __restrict__ Q,
          const unsigned short* __restrict__ Kb,
          const unsigned short* __restrict__ Vt,
          unsigned short* __restrict__ Ao)
{
    __shared__ char smem[24576];
    char* Kl0 = smem;            // [32 kv][128 k] bf16, 256B rows, XOR-swizzled chunks
    char* Kl1 = smem + 8192;
    char* Vl  = smem + 16384;    // [128 d][32 kv] bf16, 64B rows, XOR-swizzled

    // XCD remap: 8 XCDs x 3 heads x 64 q-blocks (3MB K/V per XCD fits its L2)
    const int fid = blockIdx.x;             // 0..1535
    const int xcd = fid & 7;
    const int slot = fid >> 3;              // 0..191
    const int bh = xcd * 3 + (slot >> 6);   // 0..23
    const int sblk = slot & 63;
    const int b = bh / HQ, h = bh % HQ;
    const int s0 = sblk * 32;

    const int lane = threadIdx.x;
    const int l31 = lane & 31, hi = lane >> 5;
    const float CE = 0.12751879f;           // (1/sqrt(128)) * log2(e)
    const float THR = 90.5f;                // defer-max threshold, raw-score units

    const unsigned short* Kbase = Kb + (size_t)(b * SQ) * DIMQ + h * HDQ;
    const unsigned short* Vbase = Vt + (size_t)(bh * HDQ) * SQ;

    // Q fragments (B-operand: col q = l31, k = kc*16 + hi*8 + e)
    short8 qf[8];
    {
        const unsigned short* qp = Q + (size_t)(b * SQ + s0 + l31) * DIMQ + h * HDQ;
        #pragma unroll
        for (int kc = 0; kc < 8; ++kc)
            qf[kc] = *(const short8*)(qp + kc * 16 + hi * 8);
    }
    MEMFENCE();                 // keep Q loads before the first DMA
    // prologue: K(0) -> Kl0
    #pragma unroll
    for (int i = 0; i < 8; ++i) {
        const int off = i * 1024 + lane * 16;
        int r = off >> 8, c = (off >> 4) & 15;
        gload_lds16(Kbase + (size_t)r * DIMQ + ((c ^ (r & 7)) << 3), Kl0 + i * 1024);
    }
    VMCNT(8);                   // Q settled; K(0)'s 8 DMAs in flight

    char* kcur = Kl0;
    char* knxt = Kl1;
    float mrun = -1e30f, lsum = 0.f, nm = 1e30f;   // nm = -mrun*CE
    f32x16 oacc[4] = {};        // O^T: col q = l31, row d = dt*32 + crow(r,hi)

    #pragma unroll 1
    for (int kv0 = 0; kv0 < SQ; kv0 += 32) {
        // issue V(t): [128 d][32 kv], rows 64B = 4 chunks; swz c ^ ((r>>1)&3)
        #pragma unroll
        for (int i = 0; i < 8; ++i) {
            const int off = i * 1024 + lane * 16;
            int r = off >> 6, c = (off >> 4) & 3;
            gload_lds16(Vbase + (size_t)r * SQ + kv0 + ((c ^ ((r >> 1) & 3)) << 3),
                        Vl + i * 1024);
        }
        MEMFENCE();
        // issue K(t+1) (clamped in-bounds on last iter; dup write never read)
        const int kvn = (kv0 + 32 < SQ) ? kv0 + 32 : kv0;
        #pragma unroll
        for (int i = 0; i < 8; ++i) {
            const int off = i * 1024 + lane * 16;
            int r = off >> 8, c = (off >> 4) & 15;
            gload_lds16(Kbase + (size_t)(kvn + r) * DIMQ + ((c ^ (r & 7)) << 3),
                        knxt + i * 1024);
        }

        VMCNT(16);              // K(t) landed; V(t)+K(t+1) still in flight

        // ---- S^T = K * Q^T, two independent 4-chains
        f32x16 sa = {}, sb = {};
        const int rb = l31 * 256;
        const int rx = l31 & 7;
        #pragma unroll
        for (int kc = 0; kc < 4; ++kc) {
            short8 kf = *(const short8*)(kcur + rb + (((kc * 2 + hi) ^ rx) << 4));
            sa = __builtin_amdgcn_mfma_f32_32x32x16_bf16(kf, qf[kc], sa, 0, 0, 0);
        }
        #pragma unroll
        for (int kc = 4; kc < 8; ++kc) {
            short8 kf = *(const short8*)(kcur + rb + (((kc * 2 + hi) ^ rx) << 4));
            sb = __builtin_amdgcn_mfma_f32_32x32x16_bf16(kf, qf[kc], sb, 0, 0, 0);
        }
        f32x16 s;
        #pragma unroll
        for (int r = 0; r < 16; ++r) s[r] = sa[r] + sb[r];

        // ---- online softmax (lane-local; partner lane^32 holds the other 16 kv)
        float mt[8];
        #pragma unroll
        for (int r = 0; r < 8; ++r) mt[r] = fmaxf(s[r], s[r + 8]);
        #pragma unroll
        for (int st = 4; st > 0; st >>= 1)
            #pragma unroll
            for (int r = 0; r < 4; ++r)
                if (r < st) mt[r] = fmaxf(mt[r], mt[r + st]);
        float tm = fmaxf(mt[0], __shfl_xor(mt[0], 32));
        if (!__all(tm <= mrun + THR)) {     // defer-max (T13)
            float mnew = fmaxf(mrun, tm);
            float al = __builtin_amdgcn_exp2f((mrun - mnew) * CE);
            lsum *= al;
            #pragma unroll
            for (int dt = 0; dt < 4; ++dt)
                #pragma unroll
                for (int r = 0; r < 16; ++r) oacc[dt][r] *= al;
            mrun = mnew;
            nm = -mrun * CE;
        }
        float rs = 0.f;
        #pragma unroll
        for (int r = 0; r < 16; ++r) {
            float p = __builtin_amdgcn_exp2f(__builtin_fmaf(s[r], CE, nm));
            s[r] = p; rs += p;
        }
        rs += __shfl_xor(rs, 32);
        lsum += rs;

        // ---- P -> bf16 B-frags (kv = ks*16 + hi*8 + e per word pair)
        unsigned int A0 = cvtpk_bf16(s[0], s[1]),  A1 = cvtpk_bf16(s[2], s[3]);
        unsigned int B0 = cvtpk_bf16(s[4], s[5]),  B1 = cvtpk_bf16(s[6], s[7]);
        unsigned int C0 = cvtpk_bf16(s[8], s[9]),  C1 = cvtpk_bf16(s[10], s[11]);
        unsigned int D0 = cvtpk_bf16(s[12], s[13]), D1 = cvtpk_bf16(s[14], s[15]);
        unsigned int xA0 = __shfl_xor(A0, 32), xA1 = __shfl_xor(A1, 32);
        unsigned int xB0 = __shfl_xor(B0, 32), xB1 = __shfl_xor(B1, 32);
        unsigned int xC0 = __shfl_xor(C0, 32), xC1 = __shfl_xor(C1, 32);
        unsigned int xD0 = __shfl_xor(D0, 32), xD1 = __shfl_xor(D1, 32);
        union { unsigned int w[4]; short8 v; } pf0, pf1;
        pf0.w[0] = hi ? xB0 : A0;  pf0.w[1] = hi ? xB1 : A1;
        pf0.w[2] = hi ? B0 : xA0;  pf0.w[3] = hi ? B1 : xA1;
        pf1.w[0] = hi ? xD0 : C0;  pf1.w[1] = hi ? xD1 : C1;
        pf1.w[2] = hi ? D0 : xC0;  pf1.w[3] = hi ? D1 : xC1;

        VMCNT(8);               // V(t) landed; K(t+1) still in flight

        // ---- O^T += V^T P^T  (4 independent 2-chains)
        #pragma unroll
        for (int dt = 0; dt < 4; ++dt) {
            const int drow = dt * 32 + l31;
            const int sw = (drow >> 1) & 3;
            short8 v0 = *(const short8*)(Vl + drow * 64 + ((hi ^ sw) << 4));
            short8 v1 = *(const short8*)(Vl + drow * 64 + (((2 + hi) ^ sw) << 4));
            oacc[dt] = __builtin_amdgcn_mfma_f32_32x32x16_bf16(v0, pf0.v, oacc[dt], 0, 0, 0);
            oacc[dt] = __builtin_amdgcn_mfma_f32_32x32x16_bf16(v1, pf1.v, oacc[dt], 0, 0, 0);
        }

        char* tp = kcur; kcur = knxt; knxt = tp;
    }

    // ---- epilogue: normalize, transpose O^T -> O via wave-private swizzled LDS
    // (V region; only K-prefetch DMA is in flight and it targets the K buffers)
    const float rls = 1.0f / lsum;
    char* Ot = Vl;              // [32 q][128 d] bf16, 256B rows, XOR-swizzled
    #pragma unroll
    for (int dt = 0; dt < 4; ++dt)
        #pragma unroll
        for (int rp = 0; rp < 8; ++rp) {
            const int r = 2 * rp;
            float v0 = oacc[dt][r] * rls;
            float v1 = oacc[dt][r + 1] * rls;
            int d = dt * 32 + (r & 3) + 8 * (r >> 2) + 4 * hi;   // even
            unsigned int w = (unsigned int)f2bf(v0) | ((unsigned int)f2bf(v1) << 16);
            int addr = l31 * 256 + (((d >> 3) ^ (l31 & 7)) << 4) + (d & 7) * 2;
            *(unsigned int*)(Ot + addr) = w;
        }
    #pragma unroll
    for (int ii = 0; ii < 8; ++ii) {
        int task = ii * 64 + lane;          // 32 q x 16 chunks
        int q = task >> 4, c = task & 15;
        u16x8 vv = *(const u16x8*)(Ot + q * 256 + ((c ^ (q & 7)) << 4));
        int tok = b * SQ + s0 + q;
        *(u16x8*)(Ao + (size_t)tok * DIMQ + h * HDQ + c * 8) = vv;
    }
}

// ---------------------------------------------------------------- launch
extern "C" void kernel_launch(void* const* d_in, const int* in_sizes, int n_in,
                              void* d_out, int out_size, void* d_ws, size_t ws_size,
                              hipStream_t stream) {
    (void)in_sizes; (void)n_in; (void)out_size; (void)ws_size;
    const float* x     = (const float*)d_in[0];
    const float* freqs = (const float*)d_in[1];
    const float* wq = (const float*)d_in[2];
    const float* bq = (const float*)d_in[3];
    const float* wk = (const float*)d_in[4];
    const float* bk = (const float*)d_in[5];
    const float* wv = (const float*)d_in[6];
    const float* bv = (const float*)d_in[7];
    const float* wo = (const float*)d_in[8];
    const float* bo = (const float*)d_in[9];
    const float* gq = (const float*)d_in[10];
    const float* gk = (const float*)d_in[11];
    float* out = (float*)d_out;

    char* w = (char*)d_ws;
    unsigned short* Xb   = (unsigned short*)(w);               // 4096x1536 bf16
    unsigned short* Wqkv = (unsigned short*)(w + 12582912);    // 4608x1536 bf16
    unsigned short* Wob  = (unsigned short*)(w + 26738688);    // 1536x1536 bf16
    unsigned short* Qb   = (unsigned short*)(w + 31457280);    // 4096x1536 bf16
    unsigned short* Kbuf = (unsigned short*)(w + 44040192);    // 4096x1536 bf16
    unsigned short* Vb   = (unsigned short*)(w + 56623104);    // 4096x1536 bf16
    unsigned short* Vt   = (unsigned short*)(w + 69206016);    // 24x128x2048 bf16
    unsigned short* Ao   = Xb;   // Xb dead after GEMM1 -> reuse for attention out

    cast_all<<<2048, 256, 0, stream>>>(x, wq, wk, wv, wo, Xb, Wqkv, Wob);

    gemm_bt<0><<<dim3(32, 36), 256, 0, stream>>>(
        Xb, Wqkv, Qb, Kbuf, Vb, bq, bk, bv, nullptr, nullptr);

    rmsnorm_rope<<<4096, 256, 0, stream>>>(Qb,   gq, freqs);
    rmsnorm_rope<<<4096, 256, 0, stream>>>(Kbuf, gk, freqs);
    vtrans<<<dim3(32, 2, 24), 256, 0, stream>>>(Vb, Vt);

    attn<<<1536, 64, 0, stream>>>(Qb, Kbuf, Vt, Ao);

    gemm_bt<1><<<dim3(32, 12), 256, 0, stream>>>(
        Ao, Wob, nullptr, nullptr, nullptr, nullptr, nullptr, nullptr, out, bo);
}